// Round 18
// baseline (173.992 us; speedup 1.0000x reference)
//
#include <hip/hip_runtime.h>
#include <math.h>

#define N 64
#define S 64
#define C 128
#define P 32
#define KCLS 1000
#define HPG 24
#define C3 384
#define NS 4096   /* N*S */
#define EPSV 1e-5f

// ---- workspace layout (float offsets) ----
#define WS_H    0                              // [3][P][HPG][NS]   9437184 (i-third partials)
#define WS_W1Z  (WS_H + 3*P*HPG*NS)            // [384][8][32][4]    393216
#define WS_BNSS (WS_W1Z + 384*8*32*4)          // [P*HPG][2]           1536
#define WS_Y    (WS_BNSS + P*HPG*2)            // [P][N][C3]         786432
#define WS_Z    (WS_Y + P*N*C3)                // [P][N]               2048
#define WS_PF   (WS_Z + P*N)                   // [P][C][N]          262144
#define WS_SC   (WS_PF + P*C*N)                // score [N][P][S]    131072
#define WS_MI   (WS_SC + N*P*S)                // argmax [N][P]        2048

// ============ K0w: w1[p][o][i] -> w1z[i][oq][p][4], o = oq*3 + comp ============
__global__ __launch_bounds__(256) void k0w_w1z(
    const float* __restrict__ w1, float* __restrict__ w1z)
{
  int e = blockIdx.x * 256 + threadIdx.x;   // [0, 98304)
  int p = e & 31;
  int oq = (e >> 5) & 7;
  int i = e >> 8;
  float4 v;
  v.x = w1[(p * HPG + oq * 3 + 0) * C3 + i];
  v.y = w1[(p * HPG + oq * 3 + 1) * C3 + i];
  v.z = w1[(p * HPG + oq * 3 + 2) * C3 + i];
  v.w = 0.f;
  ((float4*)w1z)[e] = v;
}

// ============ K01: partial h over i-THIRD, from RAW input (r17 + i-split x3) ====
// grid (N, 8 s-tiles, 3 i-splits), block 256: p = t&31, oq = t>>5 (3 o x 8 s).
// T14: issue next-chunk gather loads early -> compute -> barrier -> LDS write -> barrier.
__global__ __launch_bounds__(256) void k01_h(
    const float* __restrict__ tf, const float* __restrict__ ts,
    const float* __restrict__ tl, const float* __restrict__ w1z,
    float* __restrict__ h)
{
  int n = blockIdx.x, st = blockIdx.y, split = blockIdx.z;
  int s0 = st * 8;
  int t = threadIdx.x;
  int p = t & 31;
  int oq = t >> 5;            // 0..7
  __shared__ float xl[8192];  // 32 KB: dword addr = c*256 + sh*128 + p*4 + ss
  float acc[3][8];
  #pragma unroll
  for (int oo = 0; oo < 3; ++oo)
    #pragma unroll
    for (int s = 0; s < 8; ++s) acc[oo][s] = 0.f;

  const float4* w4p = (const float4*)w1z;
  const float* srcs[3] = {tf, ts, tl};

  // chunk-invariant staging decode: a -> (c, sh, pp)
  int aoff[8];
  int goff[8];
  #pragma unroll
  for (int j = 0; j < 8; ++j) {
    int a = (t + 256 * j) * 4;      // dword addr in xl
    int c  = a >> 8;
    int sh = (a >> 7) & 1;
    int pp = (a >> 2) & 31;
    aoff[j] = a;
    goff[j] = sh * 4 * C * P + c * P + pp;
  }

  float4 stg[8];
  // ---- prologue: stage chunk 0 of this split
  {
    int gch = split * 4;
    int z = gch >> 2, c0 = (gch & 3) * 32;
    const float* tb = srcs[z] + ((size_t)(n * S + s0)) * C * P + c0 * P;
    #pragma unroll
    for (int j = 0; j < 8; ++j) {
      const float* g = tb + goff[j];
      stg[j].x = g[0];
      stg[j].y = g[C * P];
      stg[j].z = g[2 * C * P];
      stg[j].w = g[3 * C * P];
    }
    #pragma unroll
    for (int j = 0; j < 8; ++j) *(float4*)&xl[aoff[j]] = stg[j];
  }
  __syncthreads();

  for (int ch = 0; ch < 4; ++ch) {
    // issue next-chunk loads early (memory pipe, no deps on xl)
    if (ch < 3) {
      int gch2 = split * 4 + ch + 1;
      int z2 = gch2 >> 2, c02 = (gch2 & 3) * 32;
      const float* tb = srcs[z2] + ((size_t)(n * S + s0)) * C * P + c02 * P;
      #pragma unroll
      for (int j = 0; j < 8; ++j) {
        const float* g = tb + goff[j];
        stg[j].x = g[0];
        stg[j].y = g[C * P];
        stg[j].z = g[2 * C * P];
        stg[j].w = g[3 * C * P];
      }
    }
    // compute current chunk from xl (hides the loads above)
    int gch = split * 4 + ch;
    #pragma unroll 4
    for (int cl = 0; cl < 32; ++cl) {
      int i = gch * 32 + cl;
      float4 w  = w4p[(i * 8 + oq) * 32 + p];          // L2-hot, coalesced
      float4 x0 = *(const float4*)&xl[cl * 256 + p * 4];        // s 0..3
      float4 x1 = *(const float4*)&xl[cl * 256 + 128 + p * 4];  // s 4..7
      acc[0][0] += w.x * x0.x; acc[0][1] += w.x * x0.y;
      acc[0][2] += w.x * x0.z; acc[0][3] += w.x * x0.w;
      acc[0][4] += w.x * x1.x; acc[0][5] += w.x * x1.y;
      acc[0][6] += w.x * x1.z; acc[0][7] += w.x * x1.w;
      acc[1][0] += w.y * x0.x; acc[1][1] += w.y * x0.y;
      acc[1][2] += w.y * x0.z; acc[1][3] += w.y * x0.w;
      acc[1][4] += w.y * x1.x; acc[1][5] += w.y * x1.y;
      acc[1][6] += w.y * x1.z; acc[1][7] += w.y * x1.w;
      acc[2][0] += w.z * x0.x; acc[2][1] += w.z * x0.y;
      acc[2][2] += w.z * x0.z; acc[2][3] += w.z * x0.w;
      acc[2][4] += w.z * x1.x; acc[2][5] += w.z * x1.y;
      acc[2][6] += w.z * x1.z; acc[2][7] += w.z * x1.w;
    }
    __syncthreads();              // all xl reads done
    if (ch < 3) {
      #pragma unroll
      for (int j = 0; j < 8; ++j) *(float4*)&xl[aoff[j]] = stg[j];  // vmcnt drains here
      __syncthreads();            // writes visible
    }
  }

  // partial-h writes (each thread owns complete 8-s runs for 3 o's)
  #pragma unroll
  for (int oo = 0; oo < 3; ++oo) {
    int o = oq * 3 + oo;
    float* hp = h + ((size_t)split * P * HPG + p * HPG + o) * NS + n * S + s0;
    *(float4*)&hp[0] = make_float4(acc[oo][0], acc[oo][1], acc[oo][2], acc[oo][3]);
    *(float4*)&hp[4] = make_float4(acc[oo][4], acc[oo][5], acc[oo][6], acc[oo][7]);
  }
}

// ============ K2: BN1 stats from the three h thirds; 768 blocks = one per (p,o) ============
__global__ __launch_bounds__(256) void k2_bnstat(const float* __restrict__ h,
    const float* __restrict__ g, const float* __restrict__ b,
    float* __restrict__ bnss)
{
  int po = blockIdx.x;             // p*HPG + o
  int t = threadIdx.x;
  const float4* r0 = (const float4*)(h + (size_t)po * NS);
  const float4* r1 = (const float4*)(h + (size_t)(P * HPG + po) * NS);
  const float4* r2 = (const float4*)(h + (size_t)(2 * P * HPG + po) * NS);
  float sm = 0.f, sq = 0.f;
  #pragma unroll
  for (int k = 0; k < 4; ++k) {
    float4 a = r0[t + 256 * k];
    float4 c = r1[t + 256 * k];
    float4 d = r2[t + 256 * k];
    float v0 = a.x + c.x + d.x, v1 = a.y + c.y + d.y;
    float v2 = a.z + c.z + d.z, v3 = a.w + c.w + d.w;
    sm += v0 + v1 + v2 + v3;
    sq += v0 * v0 + v1 * v1 + v2 * v2 + v3 * v3;
  }
  #pragma unroll
  for (int m = 1; m < 64; m <<= 1) {
    sm += __shfl_xor(sm, m, 64);
    sq += __shfl_xor(sq, m, 64);
  }
  __shared__ float red[4][2];
  int w = t >> 6;
  if ((t & 63) == 0) { red[w][0] = sm; red[w][1] = sq; }
  __syncthreads();
  if (t == 0) {
    float sum = red[0][0] + red[1][0] + red[2][0] + red[3][0];
    float ssq = red[0][1] + red[1][1] + red[2][1] + red[3][1];
    float mu  = sum / (float)NS;
    float var = ssq / (float)NS - mu * mu;
    float sc = g[po] * rsqrtf(var + EPSV);
    bnss[po * 2]     = sc;
    bnss[po * 2 + 1] = b[po] - mu * sc;
  }
}

// ============ K3a: score[n][p][s], Z, argmax (h = sum of 3 thirds) ============
__global__ __launch_bounds__(256) void k3a_score(
    const float* __restrict__ h, const float* __restrict__ bnss,
    const float* __restrict__ w2,
    float* __restrict__ score, float* __restrict__ z,
    int* __restrict__ mi_out)
{
  int n = blockIdx.x;
  int p = blockIdx.y * 4 + (threadIdx.x >> 6);
  int l = threadIdx.x & 63;   // = s
  float ssum = 0.f;
  const float* hp0 = h + (size_t)p * HPG * NS + n * S;
  const float* hp1 = hp0 + (size_t)P * HPG * NS;
  const float* hp2 = hp0 + (size_t)2 * P * HPG * NS;
  #pragma unroll
  for (int o = 0; o < HPG; ++o) {
    float hv = hp0[(size_t)o * NS + l] + hp1[(size_t)o * NS + l]
             + hp2[(size_t)o * NS + l];
    float sc = bnss[(p * HPG + o) * 2];
    float sh = bnss[(p * HPG + o) * 2 + 1];
    float v = hv * sc + sh;
    v = (v >= 0.f) ? v : 0.01f * v;
    ssum += w2[p * HPG + o] * v;
  }
  float scr = 1.f / (1.f + expf(-ssum));
  float zs = scr;
  #pragma unroll
  for (int m = 1; m < 64; m <<= 1) zs += __shfl_xor(zs, m, 64);
  float mv = scr; int mi = l;
  #pragma unroll
  for (int m = 1; m < 64; m <<= 1) {
    float ov = __shfl_xor(mv, m, 64);
    int   oi = __shfl_xor(mi, m, 64);
    if (ov > mv || (ov == mv && oi < mi)) { mv = ov; mi = oi; }
  }
  if (l == 0) { z[p * N + n] = zs; mi_out[n * P + p] = mi; }
  score[((size_t)n * P + p) * S + l] = scr;
}

// ============ K3b: y[p][n][i] = sum_s x[n,s,i,p]*score[n,p,s], raw input ====
__global__ __launch_bounds__(256) void k3b_y(
    const float* __restrict__ tf, const float* __restrict__ ts,
    const float* __restrict__ tl, const float* __restrict__ score,
    const int* __restrict__ mi, float* __restrict__ y,
    float* __restrict__ out_spf)
{
  int n = blockIdx.x, chunk = blockIdx.y;
  int z = chunk >> 2, c0 = (chunk & 3) * 32;
  const float* src = (z == 0) ? tf : (z == 1) ? ts : tl;
  int t = threadIdx.x;
  int p = t & 31, cl = t >> 5;
  __shared__ float sc_lds[S * P];   // [s][p]
  __shared__ int mi_lds[P];
  #pragma unroll
  for (int j = 0; j < 8; ++j) {
    int e = t + 256 * j;
    int s2 = e >> 5, pp = e & 31;
    sc_lds[s2 * P + pp] = score[((size_t)n * P + pp) * S + s2];
  }
  if (t < P) mi_lds[t] = mi[n * P + t];
  __syncthreads();
  int mymi = mi_lds[p];
  const float* base = src + (size_t)n * S * C * P + (size_t)(c0 + cl) * P + p;
  float acc[4] = {0.f, 0.f, 0.f, 0.f};
  float sel[4] = {0.f, 0.f, 0.f, 0.f};
  #pragma unroll 8
  for (int s = 0; s < S; ++s) {
    float scv = sc_lds[s * P + p];
    #pragma unroll
    for (int j = 0; j < 4; ++j) {
      float v = base[(size_t)s * C * P + j * 8 * P];
      acc[j] += v * scv;
      sel[j] = (s == mymi) ? v : sel[j];
    }
  }
  float* yp = y + ((size_t)p * N + n) * C3 + z * C + c0 + cl;
  #pragma unroll
  for (int j = 0; j < 4; ++j) yp[j * 8] = acc[j];
  if (z == 0) {
    float* sp = out_spf + ((size_t)p * N + n) * C + c0 + cl;
    #pragma unroll
    for (int j = 0; j < 4; ++j) sp[j * 8] = sel[j];
  }
}

// ============ K4: wpv = (wd . y)/Z, BN over n, write wpv + pf[p][c][n] ============
__global__ __launch_bounds__(256) void k4_wpv(
    const float* __restrict__ y, const float* __restrict__ z,
    const float* __restrict__ wd, const float* __restrict__ g,
    const float* __restrict__ b, float* __restrict__ out_wpv,
    float* __restrict__ pf)
{
  int p   = blockIdx.x;
  int cch = blockIdx.y;             // 0..7
  int t = threadIdx.x;
  int n = t & 63, cg = t >> 6;
  int cbase = cch * 16 + cg * 4;
  __shared__ float ych[96][66];     // i-major, stride 66 -> 2-way (free)
  float acc[4] = {0.f, 0.f, 0.f, 0.f};
  const float* yp  = y  + (size_t)p * N * C3;
  const float* wdp = wd + (size_t)p * C * C3;
  for (int ch = 0; ch < 4; ++ch) {
    __syncthreads();
    #pragma unroll
    for (int j = 0; j < 24; ++j) {
      int e = t + 256 * j;
      int i = e % 96, nn = e / 96;
      ych[i][nn] = yp[nn * C3 + ch * 96 + i];
    }
    __syncthreads();
    #pragma unroll
    for (int sub = 0; sub < 4; ++sub) {
      float yr[24];
      #pragma unroll
      for (int kk = 0; kk < 24; ++kk) yr[kk] = ych[sub * 24 + kk][n];
      int ibase = ch * 96 + sub * 24;
      #pragma unroll
      for (int cl = 0; cl < 4; ++cl) {
        const float4* w4 = (const float4*)(wdp + (size_t)(cbase + cl) * C3 + ibase);
        float a = 0.f;
        #pragma unroll
        for (int q = 0; q < 6; ++q) {
          float4 wv = w4[q];
          a += yr[q*4+0] * wv.x + yr[q*4+1] * wv.y
             + yr[q*4+2] * wv.z + yr[q*4+3] * wv.w;
        }
        acc[cl] += a;
      }
    }
  }
  float zinv = 1.f / z[p * N + n];
  #pragma unroll
  for (int cl = 0; cl < 4; ++cl) acc[cl] *= zinv;
  #pragma unroll
  for (int cl = 0; cl < 4; ++cl) {
    float v = acc[cl];
    float s = v, q = v * v;
    #pragma unroll
    for (int m = 1; m < 64; m <<= 1) {
      s += __shfl_xor(s, m, 64);
      q += __shfl_xor(q, m, 64);
    }
    float mu  = s * (1.f / 64.f);
    float var = q * (1.f / 64.f) - mu * mu;
    int c = cbase + cl;
    float sc = g[p * C + c] * rsqrtf(var + EPSV);
    float sh = b[p * C + c] - mu * sc;
    pf[((size_t)p * C + c) * N + n] = v * sc + sh;   // coalesced over n
  }
  float4 wout = make_float4(acc[0], acc[1], acc[2], acc[3]);
  *(float4*)(out_wpv + ((size_t)p * N + n) * C + cbase) = wout;
}

// ============ K5: part_classification[p][n][k] = sum_c pf[p][c][n]*fc[c][k] ============
__global__ __launch_bounds__(256) void k5_fc(
    const float* __restrict__ pf, const float* __restrict__ fc,
    float* __restrict__ out0)
{
  int kt = blockIdx.x;   // 0..3
  int p  = blockIdx.y;
  int n0 = blockIdx.z * 16;
  int t = threadIdx.x;
  int k = kt * 256 + t;
  bool ok = k < KCLS;
  int kk = ok ? k : (KCLS - 1);
  float acc[16];
  #pragma unroll
  for (int j = 0; j < 16; ++j) acc[j] = 0.f;
  for (int c = 0; c < C; ++c) {
    float fv = fc[c * KCLS + kk];
    const float4* row4 = (const float4*)(pf + ((size_t)p * C + c) * N + n0);
    #pragma unroll
    for (int j4 = 0; j4 < 4; ++j4) {
      float4 r = row4[j4];   // wave-uniform -> scalar loads
      acc[j4*4+0] += r.x * fv; acc[j4*4+1] += r.y * fv;
      acc[j4*4+2] += r.z * fv; acc[j4*4+3] += r.w * fv;
    }
  }
  if (ok) {
    #pragma unroll 4
    for (int j = 0; j < 16; ++j)
      out0[(size_t)(p * N + n0 + j) * KCLS + k] = acc[j];
  }
}

extern "C" void kernel_launch(void* const* d_in, const int* in_sizes, int n_in,
                              void* d_out, int out_size, void* d_ws, size_t ws_size,
                              hipStream_t stream)
{
  const float* tf = (const float*)d_in[0];
  const float* ts = (const float*)d_in[1];
  const float* tl = (const float*)d_in[2];
  const float* w1 = (const float*)d_in[3];
  const float* g1 = (const float*)d_in[4];
  const float* b1 = (const float*)d_in[5];
  const float* w2 = (const float*)d_in[6];
  const float* wd = (const float*)d_in[7];
  const float* g  = (const float*)d_in[8];
  const float* b  = (const float*)d_in[9];
  const float* fc = (const float*)d_in[10];

  float* ws   = (float*)d_ws;
  float* h    = ws + WS_H;
  float* w1z  = ws + WS_W1Z;
  float* bnss = ws + WS_BNSS;
  float* y    = ws + WS_Y;
  float* z    = ws + WS_Z;
  float* pf   = ws + WS_PF;
  float* sc   = ws + WS_SC;
  int*   mi   = (int*)(ws + WS_MI);

  float* out0 = (float*)d_out;         // part_classification (P,N,K)
  float* out1 = out0 + P * N * KCLS;   // weighted_part_vector (P,N,C)
  float* out2 = out1 + P * N * C;      // selected_part_feature (P,N,C)

  k0w_w1z<<<384, 256, 0, stream>>>(w1, w1z);
  k01_h<<<dim3(64, 8, 3), 256, 0, stream>>>(tf, ts, tl, w1z, h);
  k2_bnstat<<<768, 256, 0, stream>>>(h, g1, b1, bnss);
  k3a_score<<<dim3(64, 8), 256, 0, stream>>>(h, bnss, w2, sc, z, mi);
  k3b_y<<<dim3(64, 12), 256, 0, stream>>>(tf, ts, tl, sc, mi, y, out2);
  k4_wpv<<<dim3(32, 8), 256, 0, stream>>>(y, z, wd, g, b, out1, pf);
  k5_fc<<<dim3(4, 32, 4), 256, 0, stream>>>(pf, fc, out0);
}

// Round 19
// 173.971 us; speedup vs baseline: 1.0001x; 1.0001x over previous
//
#include <hip/hip_runtime.h>
#include <math.h>

#define N 64
#define S 64
#define C 128
#define P 32
#define KCLS 1000
#define HPG 24
#define C3 384
#define NS 4096   /* N*S */
#define EPSV 1e-5f

// ---- workspace layout (float offsets) ----
#define WS_H    0                              // [2][P][HPG][NS]   6291456 (i-split partials)
#define WS_W1Z  (WS_H + 2*P*HPG*NS)            // [384][4][32][8]    393216
#define WS_BNSS (WS_W1Z + 384*4*32*8)          // [P*HPG][2]           1536
#define WS_Y    (WS_BNSS + P*HPG*2)            // [P][N][C3]         786432
#define WS_Z    (WS_Y + P*N*C3)                // [P][N]               2048
#define WS_PF   (WS_Z + P*N)                   // [P][C][N]          262144
#define WS_SC   (WS_PF + P*C*N)                // score [N][P][S]    131072
#define WS_MI   (WS_SC + N*P*S)                // argmax [N][P]        2048

// ============ K0w: w1[p][o][i] -> w8[((i*4+oh)*32+p)*8 + r], o = oh*6 + r ============
// 98304 float4 -> 384 blocks x 256; r=6,7 padded 0
__global__ __launch_bounds__(256) void k0w_w1z(
    const float* __restrict__ w1, float* __restrict__ w8)
{
  int e = blockIdx.x * 256 + threadIdx.x;   // [0, 98304)
  int half = e & 1;
  int p = (e >> 1) & 31;
  int oh = (e >> 6) & 3;
  int i = e >> 8;
  float4 v;
  if (half == 0) {
    v.x = w1[(p * HPG + oh * 6 + 0) * C3 + i];
    v.y = w1[(p * HPG + oh * 6 + 1) * C3 + i];
    v.z = w1[(p * HPG + oh * 6 + 2) * C3 + i];
    v.w = w1[(p * HPG + oh * 6 + 3) * C3 + i];
  } else {
    v.x = w1[(p * HPG + oh * 6 + 4) * C3 + i];
    v.y = w1[(p * HPG + oh * 6 + 5) * C3 + i];
    v.z = 0.f; v.w = 0.f;
  }
  ((float4*)w8)[e] = v;
}

// ============ K01: partial h over i-half, from RAW input ====
// grid (N, 8 s-tiles, 2 i-splits), block 256: p=t&31, ih=(t>>5)&1, oh=t>>6.
// thread: 6 o x 8 s over a c-HALF (16 cl) -> DS b128 reads halved vs r17.
// ih-pair = lanes p, p+32 of same wave -> combine via shfl_xor(32).
// T14: issue next-chunk gather loads early -> compute -> barrier -> LDS write -> barrier.
__global__ __launch_bounds__(256) void k01_h(
    const float* __restrict__ tf, const float* __restrict__ ts,
    const float* __restrict__ tl, const float* __restrict__ w8,
    float* __restrict__ h)
{
  int n = blockIdx.x, st = blockIdx.y, split = blockIdx.z;
  int s0 = st * 8;
  int t = threadIdx.x;
  int p = t & 31;
  int ih = (t >> 5) & 1;      // c-half
  int oh = t >> 6;            // 0..3 (6 o each)
  __shared__ float xl[8192];  // 32 KB: dword addr = c*256 + sh*128 + p*4 + ss
  float acc[6][8];
  #pragma unroll
  for (int oo = 0; oo < 6; ++oo)
    #pragma unroll
    for (int s = 0; s < 8; ++s) acc[oo][s] = 0.f;

  const float* srcs[3] = {tf, ts, tl};

  // chunk-invariant staging decode: a -> (c, sh, pp)
  int aoff[8];
  int goff[8];
  #pragma unroll
  for (int j = 0; j < 8; ++j) {
    int a = (t + 256 * j) * 4;      // dword addr in xl
    int c  = a >> 8;
    int sh = (a >> 7) & 1;
    int pp = (a >> 2) & 31;
    aoff[j] = a;
    goff[j] = sh * 4 * C * P + c * P + pp;
  }

  float4 stg[8];
  // ---- prologue: stage chunk 0 of this split
  {
    int gch = split * 6;
    int z = gch >> 2, c0 = (gch & 3) * 32;
    const float* tb = srcs[z] + ((size_t)(n * S + s0)) * C * P + c0 * P;
    #pragma unroll
    for (int j = 0; j < 8; ++j) {
      const float* g = tb + goff[j];
      stg[j].x = g[0];
      stg[j].y = g[C * P];
      stg[j].z = g[2 * C * P];
      stg[j].w = g[3 * C * P];
    }
    #pragma unroll
    for (int j = 0; j < 8; ++j) *(float4*)&xl[aoff[j]] = stg[j];
  }
  __syncthreads();

  for (int ch = 0; ch < 6; ++ch) {
    // issue next-chunk loads early (memory pipe, no deps on xl)
    if (ch < 5) {
      int gch2 = split * 6 + ch + 1;
      int z2 = gch2 >> 2, c02 = (gch2 & 3) * 32;
      const float* tb = srcs[z2] + ((size_t)(n * S + s0)) * C * P + c02 * P;
      #pragma unroll
      for (int j = 0; j < 8; ++j) {
        const float* g = tb + goff[j];
        stg[j].x = g[0];
        stg[j].y = g[C * P];
        stg[j].z = g[2 * C * P];
        stg[j].w = g[3 * C * P];
      }
    }
    // compute current chunk (this thread's c-half) from xl
    int gch = split * 6 + ch;
    #pragma unroll 4
    for (int k = 0; k < 16; ++k) {
      int cl = ih * 16 + k;
      int i = gch * 32 + cl;
      const float* wb = w8 + ((size_t)(i * 4 + oh) * 32 + p) * 8;
      float4 wA = *(const float4*)wb;          // o = oh*6 + 0..3
      float2 wB = *(const float2*)(wb + 4);    // o = oh*6 + 4..5
      float4 x0 = *(const float4*)&xl[cl * 256 + p * 4];        // s 0..3
      float4 x1 = *(const float4*)&xl[cl * 256 + 128 + p * 4];  // s 4..7
      float xs[8] = {x0.x, x0.y, x0.z, x0.w, x1.x, x1.y, x1.z, x1.w};
      #pragma unroll
      for (int ss = 0; ss < 8; ++ss) {
        acc[0][ss] += wA.x * xs[ss];
        acc[1][ss] += wA.y * xs[ss];
        acc[2][ss] += wA.z * xs[ss];
        acc[3][ss] += wA.w * xs[ss];
        acc[4][ss] += wB.x * xs[ss];
        acc[5][ss] += wB.y * xs[ss];
      }
    }
    __syncthreads();              // all xl reads done
    if (ch < 5) {
      #pragma unroll
      for (int j = 0; j < 8; ++j) *(float4*)&xl[aoff[j]] = stg[j];  // vmcnt drains here
      __syncthreads();            // writes visible
    }
  }

  // combine the two c-halves: lanes p and p+32 of the same wave
  #pragma unroll
  for (int oo = 0; oo < 6; ++oo)
    #pragma unroll
    for (int ss = 0; ss < 8; ++ss)
      acc[oo][ss] += __shfl_xor(acc[oo][ss], 32, 64);

  // partial-h writes: ih=0 lanes hold full sums, write all 8 s
  if (ih == 0) {
    #pragma unroll
    for (int oo = 0; oo < 6; ++oo) {
      int o = oh * 6 + oo;
      float* hp = h + ((size_t)split * P * HPG + p * HPG + o) * NS + n * S + s0;
      *(float4*)&hp[0] = make_float4(acc[oo][0], acc[oo][1], acc[oo][2], acc[oo][3]);
      *(float4*)&hp[4] = make_float4(acc[oo][4], acc[oo][5], acc[oo][6], acc[oo][7]);
    }
  }
}

// ============ K2: BN1 stats from the two h halves; 768 blocks = one per (p,o) ============
__global__ __launch_bounds__(256) void k2_bnstat(const float* __restrict__ h,
    const float* __restrict__ g, const float* __restrict__ b,
    float* __restrict__ bnss)
{
  int po = blockIdx.x;             // p*HPG + o
  int t = threadIdx.x;
  const float4* r0 = (const float4*)(h + (size_t)po * NS);
  const float4* r1 = (const float4*)(h + (size_t)(P * HPG + po) * NS);
  float sm = 0.f, sq = 0.f;
  #pragma unroll
  for (int k = 0; k < 4; ++k) {
    float4 a = r0[t + 256 * k];
    float4 c = r1[t + 256 * k];
    float v0 = a.x + c.x, v1 = a.y + c.y, v2 = a.z + c.z, v3 = a.w + c.w;
    sm += v0 + v1 + v2 + v3;
    sq += v0 * v0 + v1 * v1 + v2 * v2 + v3 * v3;
  }
  #pragma unroll
  for (int m = 1; m < 64; m <<= 1) {
    sm += __shfl_xor(sm, m, 64);
    sq += __shfl_xor(sq, m, 64);
  }
  __shared__ float red[4][2];
  int w = t >> 6;
  if ((t & 63) == 0) { red[w][0] = sm; red[w][1] = sq; }
  __syncthreads();
  if (t == 0) {
    float sum = red[0][0] + red[1][0] + red[2][0] + red[3][0];
    float ssq = red[0][1] + red[1][1] + red[2][1] + red[3][1];
    float mu  = sum / (float)NS;
    float var = ssq / (float)NS - mu * mu;
    float sc = g[po] * rsqrtf(var + EPSV);
    bnss[po * 2]     = sc;
    bnss[po * 2 + 1] = b[po] - mu * sc;
  }
}

// ============ K3a: score[n][p][s], Z, argmax index (h = half0 + half1) ============
__global__ __launch_bounds__(256) void k3a_score(
    const float* __restrict__ h, const float* __restrict__ bnss,
    const float* __restrict__ w2,
    float* __restrict__ score, float* __restrict__ z,
    int* __restrict__ mi_out)
{
  int n = blockIdx.x;
  int p = blockIdx.y * 4 + (threadIdx.x >> 6);
  int l = threadIdx.x & 63;   // = s
  float ssum = 0.f;
  const float* hp0 = h + (size_t)p * HPG * NS + n * S;
  const float* hp1 = hp0 + (size_t)P * HPG * NS;
  #pragma unroll
  for (int o = 0; o < HPG; ++o) {
    float hv = hp0[(size_t)o * NS + l] + hp1[(size_t)o * NS + l];
    float sc = bnss[(p * HPG + o) * 2];
    float sh = bnss[(p * HPG + o) * 2 + 1];
    float v = hv * sc + sh;
    v = (v >= 0.f) ? v : 0.01f * v;
    ssum += w2[p * HPG + o] * v;
  }
  float scr = 1.f / (1.f + expf(-ssum));
  float zs = scr;
  #pragma unroll
  for (int m = 1; m < 64; m <<= 1) zs += __shfl_xor(zs, m, 64);
  float mv = scr; int mi = l;
  #pragma unroll
  for (int m = 1; m < 64; m <<= 1) {
    float ov = __shfl_xor(mv, m, 64);
    int   oi = __shfl_xor(mi, m, 64);
    if (ov > mv || (ov == mv && oi < mi)) { mv = ov; mi = oi; }
  }
  if (l == 0) { z[p * N + n] = zs; mi_out[n * P + p] = mi; }
  score[((size_t)n * P + p) * S + l] = scr;
}

// ============ K3b: y[p][n][i] = sum_s x[n,s,i,p]*score[n,p,s], raw input ====
__global__ __launch_bounds__(256) void k3b_y(
    const float* __restrict__ tf, const float* __restrict__ ts,
    const float* __restrict__ tl, const float* __restrict__ score,
    const int* __restrict__ mi, float* __restrict__ y,
    float* __restrict__ out_spf)
{
  int n = blockIdx.x, chunk = blockIdx.y;
  int z = chunk >> 2, c0 = (chunk & 3) * 32;
  const float* src = (z == 0) ? tf : (z == 1) ? ts : tl;
  int t = threadIdx.x;
  int p = t & 31, cl = t >> 5;
  __shared__ float sc_lds[S * P];   // [s][p]
  __shared__ int mi_lds[P];
  #pragma unroll
  for (int j = 0; j < 8; ++j) {
    int e = t + 256 * j;
    int s2 = e >> 5, pp = e & 31;
    sc_lds[s2 * P + pp] = score[((size_t)n * P + pp) * S + s2];
  }
  if (t < P) mi_lds[t] = mi[n * P + t];
  __syncthreads();
  int mymi = mi_lds[p];
  const float* base = src + (size_t)n * S * C * P + (size_t)(c0 + cl) * P + p;
  float acc[4] = {0.f, 0.f, 0.f, 0.f};
  float sel[4] = {0.f, 0.f, 0.f, 0.f};
  #pragma unroll 8
  for (int s = 0; s < S; ++s) {
    float scv = sc_lds[s * P + p];
    #pragma unroll
    for (int j = 0; j < 4; ++j) {
      float v = base[(size_t)s * C * P + j * 8 * P];
      acc[j] += v * scv;
      sel[j] = (s == mymi) ? v : sel[j];
    }
  }
  float* yp = y + ((size_t)p * N + n) * C3 + z * C + c0 + cl;
  #pragma unroll
  for (int j = 0; j < 4; ++j) yp[j * 8] = acc[j];
  if (z == 0) {
    float* sp = out_spf + ((size_t)p * N + n) * C + c0 + cl;
    #pragma unroll
    for (int j = 0; j < 4; ++j) sp[j * 8] = sel[j];
  }
}

// ============ K4: wpv = (wd . y)/Z, BN over n, write wpv + pf[p][c][n] ============
__global__ __launch_bounds__(256) void k4_wpv(
    const float* __restrict__ y, const float* __restrict__ z,
    const float* __restrict__ wd, const float* __restrict__ g,
    const float* __restrict__ b, float* __restrict__ out_wpv,
    float* __restrict__ pf)
{
  int p   = blockIdx.x;
  int cch = blockIdx.y;             // 0..7
  int t = threadIdx.x;
  int n = t & 63, cg = t >> 6;
  int cbase = cch * 16 + cg * 4;
  __shared__ float ych[96][66];     // i-major, stride 66 -> 2-way (free)
  float acc[4] = {0.f, 0.f, 0.f, 0.f};
  const float* yp  = y  + (size_t)p * N * C3;
  const float* wdp = wd + (size_t)p * C * C3;
  for (int ch = 0; ch < 4; ++ch) {
    __syncthreads();
    #pragma unroll
    for (int j = 0; j < 24; ++j) {
      int e = t + 256 * j;
      int i = e % 96, nn = e / 96;
      ych[i][nn] = yp[nn * C3 + ch * 96 + i];
    }
    __syncthreads();
    #pragma unroll
    for (int sub = 0; sub < 4; ++sub) {
      float yr[24];
      #pragma unroll
      for (int kk = 0; kk < 24; ++kk) yr[kk] = ych[sub * 24 + kk][n];
      int ibase = ch * 96 + sub * 24;
      #pragma unroll
      for (int cl = 0; cl < 4; ++cl) {
        const float4* w4 = (const float4*)(wdp + (size_t)(cbase + cl) * C3 + ibase);
        float a = 0.f;
        #pragma unroll
        for (int q = 0; q < 6; ++q) {
          float4 wv = w4[q];
          a += yr[q*4+0] * wv.x + yr[q*4+1] * wv.y
             + yr[q*4+2] * wv.z + yr[q*4+3] * wv.w;
        }
        acc[cl] += a;
      }
    }
  }
  float zinv = 1.f / z[p * N + n];
  #pragma unroll
  for (int cl = 0; cl < 4; ++cl) acc[cl] *= zinv;
  #pragma unroll
  for (int cl = 0; cl < 4; ++cl) {
    float v = acc[cl];
    float s = v, q = v * v;
    #pragma unroll
    for (int m = 1; m < 64; m <<= 1) {
      s += __shfl_xor(s, m, 64);
      q += __shfl_xor(q, m, 64);
    }
    float mu  = s * (1.f / 64.f);
    float var = q * (1.f / 64.f) - mu * mu;
    int c = cbase + cl;
    float sc = g[p * C + c] * rsqrtf(var + EPSV);
    float sh = b[p * C + c] - mu * sc;
    pf[((size_t)p * C + c) * N + n] = v * sc + sh;   // coalesced over n
  }
  float4 wout = make_float4(acc[0], acc[1], acc[2], acc[3]);
  *(float4*)(out_wpv + ((size_t)p * N + n) * C + cbase) = wout;
}

// ============ K5: part_classification[p][n][k] = sum_c pf[p][c][n]*fc[c][k] ============
__global__ __launch_bounds__(256) void k5_fc(
    const float* __restrict__ pf, const float* __restrict__ fc,
    float* __restrict__ out0)
{
  int kt = blockIdx.x;   // 0..3
  int p  = blockIdx.y;
  int n0 = blockIdx.z * 16;
  int t = threadIdx.x;
  int k = kt * 256 + t;
  bool ok = k < KCLS;
  int kk = ok ? k : (KCLS - 1);
  float acc[16];
  #pragma unroll
  for (int j = 0; j < 16; ++j) acc[j] = 0.f;
  for (int c = 0; c < C; ++c) {
    float fv = fc[c * KCLS + kk];
    const float4* row4 = (const float4*)(pf + ((size_t)p * C + c) * N + n0);
    #pragma unroll
    for (int j4 = 0; j4 < 4; ++j4) {
      float4 r = row4[j4];   // wave-uniform -> scalar loads
      acc[j4*4+0] += r.x * fv; acc[j4*4+1] += r.y * fv;
      acc[j4*4+2] += r.z * fv; acc[j4*4+3] += r.w * fv;
    }
  }
  if (ok) {
    #pragma unroll 4
    for (int j = 0; j < 16; ++j)
      out0[(size_t)(p * N + n0 + j) * KCLS + k] = acc[j];
  }
}

extern "C" void kernel_launch(void* const* d_in, const int* in_sizes, int n_in,
                              void* d_out, int out_size, void* d_ws, size_t ws_size,
                              hipStream_t stream)
{
  const float* tf = (const float*)d_in[0];
  const float* ts = (const float*)d_in[1];
  const float* tl = (const float*)d_in[2];
  const float* w1 = (const float*)d_in[3];
  const float* g1 = (const float*)d_in[4];
  const float* b1 = (const float*)d_in[5];
  const float* w2 = (const float*)d_in[6];
  const float* wd = (const float*)d_in[7];
  const float* g  = (const float*)d_in[8];
  const float* b  = (const float*)d_in[9];
  const float* fc = (const float*)d_in[10];

  float* ws   = (float*)d_ws;
  float* h    = ws + WS_H;
  float* w8   = ws + WS_W1Z;
  float* bnss = ws + WS_BNSS;
  float* y    = ws + WS_Y;
  float* z    = ws + WS_Z;
  float* pf   = ws + WS_PF;
  float* sc   = ws + WS_SC;
  int*   mi   = (int*)(ws + WS_MI);

  float* out0 = (float*)d_out;         // part_classification (P,N,K)
  float* out1 = out0 + P * N * KCLS;   // weighted_part_vector (P,N,C)
  float* out2 = out1 + P * N * C;      // selected_part_feature (P,N,C)

  k0w_w1z<<<384, 256, 0, stream>>>(w1, w8);
  k01_h<<<dim3(64, 8, 2), 256, 0, stream>>>(tf, ts, tl, w8, h);
  k2_bnstat<<<768, 256, 0, stream>>>(h, g1, b1, bnss);
  k3a_score<<<dim3(64, 8), 256, 0, stream>>>(h, bnss, w2, sc, z, mi);
  k3b_y<<<dim3(64, 12), 256, 0, stream>>>(tf, ts, tl, sc, mi, y, out2);
  k4_wpv<<<dim3(32, 8), 256, 0, stream>>>(y, z, wd, g, b, out1, pf);
  k5_fc<<<dim3(4, 32, 4), 256, 0, stream>>>(pf, fc, out0);
}

// Round 20
// 158.888 us; speedup vs baseline: 1.0951x; 1.0949x over previous
//
#include <hip/hip_runtime.h>
#include <math.h>

#define N 64
#define S 64
#define C 128
#define P 32
#define KCLS 1000
#define HPG 24
#define C3 384
#define NS 4096   /* N*S */
#define EPSV 1e-5f

// ---- workspace layout (float offsets) ----
#define WS_H    0                              // [2][P][HPG][NS]   6291456 (i-split partials)
#define WS_W1Z  (WS_H + 2*P*HPG*NS)            // [384][8][32][4]    393216
#define WS_BNSS (WS_W1Z + 384*8*32*4)          // [P*HPG][2]           1536
#define WS_Y    (WS_BNSS + P*HPG*2)            // [P][N][C3]         786432
#define WS_Z    (WS_Y + P*N*C3)                // [P][N]               2048
#define WS_PF   (WS_Z + P*N)                   // [P][C][N]          262144
#define WS_SC   (WS_PF + P*C*N)                // score [N][P][S]    131072
#define WS_MI   (WS_SC + N*P*S)                // argmax [N][P]        2048

// ============ K0w: w1[p][o][i] -> w1z[i][oq][p][4], o = oq*3 + comp ============
__global__ __launch_bounds__(256) void k0w_w1z(
    const float* __restrict__ w1, float* __restrict__ w1z)
{
  int e = blockIdx.x * 256 + threadIdx.x;   // [0, 98304)
  int p = e & 31;
  int oq = (e >> 5) & 7;
  int i = e >> 8;
  float4 v;
  v.x = w1[(p * HPG + oq * 3 + 0) * C3 + i];
  v.y = w1[(p * HPG + oq * 3 + 1) * C3 + i];
  v.z = w1[(p * HPG + oq * 3 + 2) * C3 + i];
  v.w = 0.f;
  ((float4*)w1z)[e] = v;
}

// ============ K01: partial h over i-half, from RAW input (r15 + T14 async-stage) ====
// grid (N, 8 s-tiles, 2 i-splits), block 256: p = t&31, oq = t>>5 (3 o x 8 s).
// Per chunk: issue next-chunk gather loads to REGS (early) -> compute current
// from LDS (hides HBM latency) -> barrier -> write regs to LDS -> barrier.
__global__ __launch_bounds__(256) void k01_h(
    const float* __restrict__ tf, const float* __restrict__ ts,
    const float* __restrict__ tl, const float* __restrict__ w1z,
    float* __restrict__ h)
{
  int n = blockIdx.x, st = blockIdx.y, split = blockIdx.z;
  int s0 = st * 8;
  int t = threadIdx.x;
  int p = t & 31;
  int oq = t >> 5;            // 0..7
  __shared__ float xl[8192];  // 32 KB: dword addr = c*256 + sh*128 + p*4 + ss
  float acc[3][8];
  #pragma unroll
  for (int oo = 0; oo < 3; ++oo)
    #pragma unroll
    for (int s = 0; s < 8; ++s) acc[oo][s] = 0.f;

  const float4* w4p = (const float4*)w1z;
  const float* srcs[3] = {tf, ts, tl};

  // chunk-invariant staging decode: a -> (c, sh, pp)
  int aoff[8];
  int goff[8];
  #pragma unroll
  for (int j = 0; j < 8; ++j) {
    int a = (t + 256 * j) * 4;      // dword addr in xl
    int c  = a >> 8;
    int sh = (a >> 7) & 1;
    int pp = (a >> 2) & 31;
    aoff[j] = a;
    goff[j] = sh * 4 * C * P + c * P + pp;
  }

  float4 stg[8];
  // ---- prologue: stage chunk 0
  {
    int gch = split * 6;
    int z = gch >> 2, c0 = (gch & 3) * 32;
    const float* tb = srcs[z] + ((size_t)(n * S + s0)) * C * P + c0 * P;
    #pragma unroll
    for (int j = 0; j < 8; ++j) {
      const float* g = tb + goff[j];
      stg[j].x = g[0];
      stg[j].y = g[C * P];
      stg[j].z = g[2 * C * P];
      stg[j].w = g[3 * C * P];
    }
    #pragma unroll
    for (int j = 0; j < 8; ++j) *(float4*)&xl[aoff[j]] = stg[j];
  }
  __syncthreads();

  for (int ch = 0; ch < 6; ++ch) {
    // issue next-chunk loads early (memory pipe, no deps on xl)
    if (ch < 5) {
      int gch2 = split * 6 + ch + 1;
      int z2 = gch2 >> 2, c02 = (gch2 & 3) * 32;
      const float* tb = srcs[z2] + ((size_t)(n * S + s0)) * C * P + c02 * P;
      #pragma unroll
      for (int j = 0; j < 8; ++j) {
        const float* g = tb + goff[j];
        stg[j].x = g[0];
        stg[j].y = g[C * P];
        stg[j].z = g[2 * C * P];
        stg[j].w = g[3 * C * P];
      }
    }
    // compute current chunk from xl (hides the loads above)
    int gch = split * 6 + ch;
    #pragma unroll 4
    for (int cl = 0; cl < 32; ++cl) {
      int i = gch * 32 + cl;
      float4 w  = w4p[(i * 8 + oq) * 32 + p];          // L2-hot, coalesced
      float4 x0 = *(const float4*)&xl[cl * 256 + p * 4];        // s 0..3
      float4 x1 = *(const float4*)&xl[cl * 256 + 128 + p * 4];  // s 4..7
      acc[0][0] += w.x * x0.x; acc[0][1] += w.x * x0.y;
      acc[0][2] += w.x * x0.z; acc[0][3] += w.x * x0.w;
      acc[0][4] += w.x * x1.x; acc[0][5] += w.x * x1.y;
      acc[0][6] += w.x * x1.z; acc[0][7] += w.x * x1.w;
      acc[1][0] += w.y * x0.x; acc[1][1] += w.y * x0.y;
      acc[1][2] += w.y * x0.z; acc[1][3] += w.y * x0.w;
      acc[1][4] += w.y * x1.x; acc[1][5] += w.y * x1.y;
      acc[1][6] += w.y * x1.z; acc[1][7] += w.y * x1.w;
      acc[2][0] += w.z * x0.x; acc[2][1] += w.z * x0.y;
      acc[2][2] += w.z * x0.z; acc[2][3] += w.z * x0.w;
      acc[2][4] += w.z * x1.x; acc[2][5] += w.z * x1.y;
      acc[2][6] += w.z * x1.z; acc[2][7] += w.z * x1.w;
    }
    __syncthreads();              // all xl reads done
    if (ch < 5) {
      #pragma unroll
      for (int j = 0; j < 8; ++j) *(float4*)&xl[aoff[j]] = stg[j];  // vmcnt drains here
      __syncthreads();            // writes visible
    }
  }

  // partial-h writes (each thread owns complete 8-s runs for 3 o's)
  #pragma unroll
  for (int oo = 0; oo < 3; ++oo) {
    int o = oq * 3 + oo;
    float* hp = h + ((size_t)split * P * HPG + p * HPG + o) * NS + n * S + s0;
    *(float4*)&hp[0] = make_float4(acc[oo][0], acc[oo][1], acc[oo][2], acc[oo][3]);
    *(float4*)&hp[4] = make_float4(acc[oo][4], acc[oo][5], acc[oo][6], acc[oo][7]);
  }
}

// ============ K2: BN1 stats from the two h halves; 768 blocks = one per (p,o) ============
__global__ __launch_bounds__(256) void k2_bnstat(const float* __restrict__ h,
    const float* __restrict__ g, const float* __restrict__ b,
    float* __restrict__ bnss)
{
  int po = blockIdx.x;             // p*HPG + o
  int t = threadIdx.x;
  const float4* r0 = (const float4*)(h + (size_t)po * NS);
  const float4* r1 = (const float4*)(h + (size_t)(P * HPG + po) * NS);
  float sm = 0.f, sq = 0.f;
  #pragma unroll
  for (int k = 0; k < 4; ++k) {
    float4 a = r0[t + 256 * k];
    float4 c = r1[t + 256 * k];
    float v0 = a.x + c.x, v1 = a.y + c.y, v2 = a.z + c.z, v3 = a.w + c.w;
    sm += v0 + v1 + v2 + v3;
    sq += v0 * v0 + v1 * v1 + v2 * v2 + v3 * v3;
  }
  #pragma unroll
  for (int m = 1; m < 64; m <<= 1) {
    sm += __shfl_xor(sm, m, 64);
    sq += __shfl_xor(sq, m, 64);
  }
  __shared__ float red[4][2];
  int w = t >> 6;
  if ((t & 63) == 0) { red[w][0] = sm; red[w][1] = sq; }
  __syncthreads();
  if (t == 0) {
    float sum = red[0][0] + red[1][0] + red[2][0] + red[3][0];
    float ssq = red[0][1] + red[1][1] + red[2][1] + red[3][1];
    float mu  = sum / (float)NS;
    float var = ssq / (float)NS - mu * mu;
    float sc = g[po] * rsqrtf(var + EPSV);
    bnss[po * 2]     = sc;
    bnss[po * 2 + 1] = b[po] - mu * sc;
  }
}

// ============ K3a: score[n][p][s], Z, argmax index (h = half0 + half1) ============
__global__ __launch_bounds__(256) void k3a_score(
    const float* __restrict__ h, const float* __restrict__ bnss,
    const float* __restrict__ w2,
    float* __restrict__ score, float* __restrict__ z,
    int* __restrict__ mi_out)
{
  int n = blockIdx.x;
  int p = blockIdx.y * 4 + (threadIdx.x >> 6);
  int l = threadIdx.x & 63;   // = s
  float ssum = 0.f;
  const float* hp0 = h + (size_t)p * HPG * NS + n * S;
  const float* hp1 = hp0 + (size_t)P * HPG * NS;
  #pragma unroll
  for (int o = 0; o < HPG; ++o) {
    float hv = hp0[(size_t)o * NS + l] + hp1[(size_t)o * NS + l];
    float sc = bnss[(p * HPG + o) * 2];
    float sh = bnss[(p * HPG + o) * 2 + 1];
    float v = hv * sc + sh;
    v = (v >= 0.f) ? v : 0.01f * v;
    ssum += w2[p * HPG + o] * v;
  }
  float scr = 1.f / (1.f + expf(-ssum));
  float zs = scr;
  #pragma unroll
  for (int m = 1; m < 64; m <<= 1) zs += __shfl_xor(zs, m, 64);
  float mv = scr; int mi = l;
  #pragma unroll
  for (int m = 1; m < 64; m <<= 1) {
    float ov = __shfl_xor(mv, m, 64);
    int   oi = __shfl_xor(mi, m, 64);
    if (ov > mv || (ov == mv && oi < mi)) { mv = ov; mi = oi; }
  }
  if (l == 0) { z[p * N + n] = zs; mi_out[n * P + p] = mi; }
  score[((size_t)n * P + p) * S + l] = scr;
}

// ============ K3b: y[p][n][i] = sum_s x[n,s,i,p]*score[n,p,s], raw input ====
__global__ __launch_bounds__(256) void k3b_y(
    const float* __restrict__ tf, const float* __restrict__ ts,
    const float* __restrict__ tl, const float* __restrict__ score,
    const int* __restrict__ mi, float* __restrict__ y,
    float* __restrict__ out_spf)
{
  int n = blockIdx.x, chunk = blockIdx.y;
  int z = chunk >> 2, c0 = (chunk & 3) * 32;
  const float* src = (z == 0) ? tf : (z == 1) ? ts : tl;
  int t = threadIdx.x;
  int p = t & 31, cl = t >> 5;
  __shared__ float sc_lds[S * P];   // [s][p]
  __shared__ int mi_lds[P];
  #pragma unroll
  for (int j = 0; j < 8; ++j) {
    int e = t + 256 * j;
    int s2 = e >> 5, pp = e & 31;
    sc_lds[s2 * P + pp] = score[((size_t)n * P + pp) * S + s2];
  }
  if (t < P) mi_lds[t] = mi[n * P + t];
  __syncthreads();
  int mymi = mi_lds[p];
  const float* base = src + (size_t)n * S * C * P + (size_t)(c0 + cl) * P + p;
  float acc[4] = {0.f, 0.f, 0.f, 0.f};
  float sel[4] = {0.f, 0.f, 0.f, 0.f};
  #pragma unroll 8
  for (int s = 0; s < S; ++s) {
    float scv = sc_lds[s * P + p];
    #pragma unroll
    for (int j = 0; j < 4; ++j) {
      float v = base[(size_t)s * C * P + j * 8 * P];
      acc[j] += v * scv;
      sel[j] = (s == mymi) ? v : sel[j];
    }
  }
  float* yp = y + ((size_t)p * N + n) * C3 + z * C + c0 + cl;
  #pragma unroll
  for (int j = 0; j < 4; ++j) yp[j * 8] = acc[j];
  if (z == 0) {
    float* sp = out_spf + ((size_t)p * N + n) * C + c0 + cl;
    #pragma unroll
    for (int j = 0; j < 4; ++j) sp[j * 8] = sel[j];
  }
}

// ============ K4: wpv = (wd . y)/Z, BN over n, write wpv + pf[p][c][n] ============
__global__ __launch_bounds__(256) void k4_wpv(
    const float* __restrict__ y, const float* __restrict__ z,
    const float* __restrict__ wd, const float* __restrict__ g,
    const float* __restrict__ b, float* __restrict__ out_wpv,
    float* __restrict__ pf)
{
  int p   = blockIdx.x;
  int cch = blockIdx.y;             // 0..7
  int t = threadIdx.x;
  int n = t & 63, cg = t >> 6;
  int cbase = cch * 16 + cg * 4;
  __shared__ float ych[96][66];     // i-major, stride 66 -> 2-way (free)
  float acc[4] = {0.f, 0.f, 0.f, 0.f};
  const float* yp  = y  + (size_t)p * N * C3;
  const float* wdp = wd + (size_t)p * C * C3;
  for (int ch = 0; ch < 4; ++ch) {
    __syncthreads();
    #pragma unroll
    for (int j = 0; j < 24; ++j) {
      int e = t + 256 * j;
      int i = e % 96, nn = e / 96;
      ych[i][nn] = yp[nn * C3 + ch * 96 + i];
    }
    __syncthreads();
    #pragma unroll
    for (int sub = 0; sub < 4; ++sub) {
      float yr[24];
      #pragma unroll
      for (int kk = 0; kk < 24; ++kk) yr[kk] = ych[sub * 24 + kk][n];
      int ibase = ch * 96 + sub * 24;
      #pragma unroll
      for (int cl = 0; cl < 4; ++cl) {
        const float4* w4 = (const float4*)(wdp + (size_t)(cbase + cl) * C3 + ibase);
        float a = 0.f;
        #pragma unroll
        for (int q = 0; q < 6; ++q) {
          float4 wv = w4[q];
          a += yr[q*4+0] * wv.x + yr[q*4+1] * wv.y
             + yr[q*4+2] * wv.z + yr[q*4+3] * wv.w;
        }
        acc[cl] += a;
      }
    }
  }
  float zinv = 1.f / z[p * N + n];
  #pragma unroll
  for (int cl = 0; cl < 4; ++cl) acc[cl] *= zinv;
  #pragma unroll
  for (int cl = 0; cl < 4; ++cl) {
    float v = acc[cl];
    float s = v, q = v * v;
    #pragma unroll
    for (int m = 1; m < 64; m <<= 1) {
      s += __shfl_xor(s, m, 64);
      q += __shfl_xor(q, m, 64);
    }
    float mu  = s * (1.f / 64.f);
    float var = q * (1.f / 64.f) - mu * mu;
    int c = cbase + cl;
    float sc = g[p * C + c] * rsqrtf(var + EPSV);
    float sh = b[p * C + c] - mu * sc;
    pf[((size_t)p * C + c) * N + n] = v * sc + sh;   // coalesced over n
  }
  float4 wout = make_float4(acc[0], acc[1], acc[2], acc[3]);
  *(float4*)(out_wpv + ((size_t)p * N + n) * C + cbase) = wout;
}

// ============ K5: part_classification[p][n][k] = sum_c pf[p][c][n]*fc[c][k] ============
__global__ __launch_bounds__(256) void k5_fc(
    const float* __restrict__ pf, const float* __restrict__ fc,
    float* __restrict__ out0)
{
  int kt = blockIdx.x;   // 0..3
  int p  = blockIdx.y;
  int n0 = blockIdx.z * 16;
  int t = threadIdx.x;
  int k = kt * 256 + t;
  bool ok = k < KCLS;
  int kk = ok ? k : (KCLS - 1);
  float acc[16];
  #pragma unroll
  for (int j = 0; j < 16; ++j) acc[j] = 0.f;
  for (int c = 0; c < C; ++c) {
    float fv = fc[c * KCLS + kk];
    const float4* row4 = (const float4*)(pf + ((size_t)p * C + c) * N + n0);
    #pragma unroll
    for (int j4 = 0; j4 < 4; ++j4) {
      float4 r = row4[j4];   // wave-uniform -> scalar loads
      acc[j4*4+0] += r.x * fv; acc[j4*4+1] += r.y * fv;
      acc[j4*4+2] += r.z * fv; acc[j4*4+3] += r.w * fv;
    }
  }
  if (ok) {
    #pragma unroll 4
    for (int j = 0; j < 16; ++j)
      out0[(size_t)(p * N + n0 + j) * KCLS + k] = acc[j];
  }
}

extern "C" void kernel_launch(void* const* d_in, const int* in_sizes, int n_in,
                              void* d_out, int out_size, void* d_ws, size_t ws_size,
                              hipStream_t stream)
{
  const float* tf = (const float*)d_in[0];
  const float* ts = (const float*)d_in[1];
  const float* tl = (const float*)d_in[2];
  const float* w1 = (const float*)d_in[3];
  const float* g1 = (const float*)d_in[4];
  const float* b1 = (const float*)d_in[5];
  const float* w2 = (const float*)d_in[6];
  const float* wd = (const float*)d_in[7];
  const float* g  = (const float*)d_in[8];
  const float* b  = (const float*)d_in[9];
  const float* fc = (const float*)d_in[10];

  float* ws   = (float*)d_ws;
  float* h    = ws + WS_H;
  float* w1z  = ws + WS_W1Z;
  float* bnss = ws + WS_BNSS;
  float* y    = ws + WS_Y;
  float* z    = ws + WS_Z;
  float* pf   = ws + WS_PF;
  float* sc   = ws + WS_SC;
  int*   mi   = (int*)(ws + WS_MI);

  float* out0 = (float*)d_out;         // part_classification (P,N,K)
  float* out1 = out0 + P * N * KCLS;   // weighted_part_vector (P,N,C)
  float* out2 = out1 + P * N * C;      // selected_part_feature (P,N,C)

  k0w_w1z<<<384, 256, 0, stream>>>(w1, w1z);
  k01_h<<<dim3(64, 8, 2), 256, 0, stream>>>(tf, ts, tl, w1z, h);
  k2_bnstat<<<768, 256, 0, stream>>>(h, g1, b1, bnss);
  k3a_score<<<dim3(64, 8), 256, 0, stream>>>(h, bnss, w2, sc, z, mi);
  k3b_y<<<dim3(64, 12), 256, 0, stream>>>(tf, ts, tl, sc, mi, y, out2);
  k4_wpv<<<dim3(32, 8), 256, 0, stream>>>(y, z, wd, g, b, out1, pf);
  k5_fc<<<dim3(4, 32, 4), 256, 0, stream>>>(pf, fc, out0);
}